// Round 12
// baseline (226.682 us; speedup 1.0000x reference)
//
#include <hip/hip_runtime.h>

// WCSA: B=2, N=4096, Cc=C=512, Cs=128, H=8, dc=d=64, ds=16.
// Internal compute: bf16 MFMA + fp32 accumulation. I/O dtype runtime-detected
// (fp32 confirmed; bf16 path kept).
//
// Head layout: reshape(B,N,C)->(B,H,N,d) direct => head h of a projection is
// the contiguous 512-row slab, row-major (4096,d).
//
// R19: proj_gemm 64(M)x128(N) tiles. Fallback proj grids were 64x8=512 and
// 64x5=320 blocks -> 2 (1.25) blocks/CU x 256 thr = 8 (5) waves/CU = 25%
// occupancy CEILING, with the fp32 path's heavy staging VALU (16 loads +
// 64 cvt/K-step) exposed to latency. 64x128 tile -> grid 128 x ntiles =
// 4 blocks/CU (16 waves/CU), A-staging halved, acc 64->32 regs, prefetch
// 8->4 (VGPR ~170->~120). Cost: B (weights, small operand) re-read 2x =
// ~1MB/launch, L2-absorbed. Wave layout 1Mx4N, wave tile 64x32 = 4x2 MFMA.
// All else byte-identical; flash = control (~70us).

typedef __attribute__((ext_vector_type(8))) __bf16 bf16x8;
typedef __attribute__((ext_vector_type(4))) __bf16 bf16x4;
typedef __attribute__((ext_vector_type(4))) float  f32x4;
typedef __attribute__((ext_vector_type(4))) short  s16x4;

#define LOG2E 1.44269504088896340736f

// 16x16x16 bf16 MFMA: A/B = 4 bf16 (2 VGPRs), C/D = 4 f32.
static __device__ __forceinline__ f32x4 mfma16(bf16x4 a, bf16x4 b, f32x4 c)
{
#if __has_builtin(__builtin_amdgcn_mfma_f32_16x16x16bf16_1k)
    union { bf16x4 h; s16x4 s; } ua, ub;
    ua.h = a; ub.h = b;
    return __builtin_amdgcn_mfma_f32_16x16x16bf16_1k(ua.s, ub.s, c, 0, 0, 0);
#elif __has_builtin(__builtin_amdgcn_mfma_f32_16x16x16_bf16)
    return __builtin_amdgcn_mfma_f32_16x16x16_bf16(a, b, c, 0, 0, 0);
#else
    asm("v_mfma_f32_16x16x16_bf16 %0, %1, %2, %0" : "+v"(c) : "v"(a), "v"(b));
    return c;
#endif
}

// ---------------------------------------------------------------------------
__global__ void detect_dtype(const unsigned* __restrict__ temp, int* __restrict__ flag)
{
    if (threadIdx.x == 0) {
        const unsigned w = temp[0];
        flag[0] = ((w >> 16) == (w & 0xffffu)) ? 1 : 0;  // 1 = bf16 I/O
    }
}

// ---------------------------------------------------------------------------
// Fused projection GEMMs, 64(M)x128(N) tile, BK=64, register prefetch.
// 4 waves in 1(M)x4(N); wave tile 64x32 = 4x2 of 16x16x32 MFMA (16 MFMA/iter).
// blockIdx.y -> group via prefix table in units of 128-wide N-tiles.
// LDS row stride 72 bf16.
// ---------------------------------------------------------------------------
struct ProjArgs {
    const void* X[6];
    const void* W[6];
    __bf16*     Y[6];
    int         K[6];
    int         yofs[7];  // units of 128-wide N tiles
    int         ng;
};

__global__ __launch_bounds__(256) void proj_gemm(ProjArgs args,
                                                 const int* __restrict__ flag)
{
    __shared__ __align__(16) __bf16 As[64][72];
    __shared__ __align__(16) __bf16 Bs[128][72];
    const int bf = *flag;
    const int by = blockIdx.y;
    int g = 0;
    while (by >= args.yofs[g + 1]) ++g;  // <=6 iters, wave-uniform
    const int n0 = (by - args.yofs[g]) * 128;
    const int N  = (args.yofs[g + 1] - args.yofs[g]) * 128;
    const int K  = args.K[g];
    const void* X = args.X[g];
    const void* W = args.W[g];
    __bf16*     Y = args.Y[g];

    const int m0 = blockIdx.x * 64;
    const int t = threadIdx.x;
    const int wave = t >> 6, lane = t & 63;
    const int wc = wave * 32;
    const int m16 = lane & 15, quad = lane >> 4;

    f32x4 acc[4][2];
#pragma unroll
    for (int i = 0; i < 4; ++i)
#pragma unroll
        for (int j = 0; j < 2; ++j) acc[i][j] = (f32x4){0.f, 0.f, 0.f, 0.f};

    if (bf) {
        // ---- bf16 inputs: prefetch A 2x + B 4x bf16x8 ----
        const __bf16* Xb = (const __bf16*)X;
        const __bf16* Wb = (const __bf16*)W;
        bf16x8 pa[2], pb[4];
        auto load = [&](int k0) {
#pragma unroll
            for (int i = 0; i < 2; ++i) {
                const int idx = t + i * 256, row = idx >> 3, off = (idx & 7) * 8;
                pa[i] = *(const bf16x8*)(Xb + (size_t)(m0 + row) * K + k0 + off);
            }
#pragma unroll
            for (int i = 0; i < 4; ++i) {
                const int idx = t + i * 256, row = idx >> 3, off = (idx & 7) * 8;
                pb[i] = *(const bf16x8*)(Wb + (size_t)(n0 + row) * K + k0 + off);
            }
        };
        load(0);
        for (int k0 = 0; k0 < K; k0 += 64) {
            __syncthreads();
#pragma unroll
            for (int i = 0; i < 2; ++i) {
                const int idx = t + i * 256, row = idx >> 3, off = (idx & 7) * 8;
                *(bf16x8*)&As[row][off] = pa[i];
            }
#pragma unroll
            for (int i = 0; i < 4; ++i) {
                const int idx = t + i * 256, row = idx >> 3, off = (idx & 7) * 8;
                *(bf16x8*)&Bs[row][off] = pb[i];
            }
            __syncthreads();
            if (k0 + 64 < K) load(k0 + 64);
#pragma unroll
            for (int kc = 0; kc < 2; ++kc) {
                const int ko = kc * 32 + quad * 8;
                bf16x8 a[4], b[2];
#pragma unroll
                for (int i = 0; i < 4; ++i) a[i] = *(const bf16x8*)&As[i * 16 + m16][ko];
#pragma unroll
                for (int j = 0; j < 2; ++j) b[j] = *(const bf16x8*)&Bs[wc + j * 16 + m16][ko];
#pragma unroll
                for (int i = 0; i < 4; ++i)
#pragma unroll
                    for (int j = 0; j < 2; ++j)
                        acc[i][j] = __builtin_amdgcn_mfma_f32_16x16x32_bf16(a[i], b[j], acc[i][j], 0, 0, 0);
            }
        }
    } else {
        // ---- fp32 inputs: prefetch A 4x + B 8x f32x4 (cvt at store) ----
        const float* Xf = (const float*)X;
        const float* Wf = (const float*)W;
        f32x4 pa[4], pb[8];
        auto load = [&](int k0) {
#pragma unroll
            for (int i = 0; i < 4; ++i) {
                const int idx = t + i * 256, row = idx >> 4, c = (idx & 15) * 4;
                pa[i] = *(const f32x4*)(Xf + (size_t)(m0 + row) * K + k0 + c);
            }
#pragma unroll
            for (int i = 0; i < 8; ++i) {
                const int idx = t + i * 256, row = idx >> 4, c = (idx & 15) * 4;
                pb[i] = *(const f32x4*)(Wf + (size_t)(n0 + row) * K + k0 + c);
            }
        };
        load(0);
        for (int k0 = 0; k0 < K; k0 += 64) {
            __syncthreads();
#pragma unroll
            for (int i = 0; i < 4; ++i) {
                const int idx = t + i * 256, row = idx >> 4, c = (idx & 15) * 4;
                bf16x4 ha;
#pragma unroll
                for (int e = 0; e < 4; ++e) ha[e] = (__bf16)pa[i][e];
                *(bf16x4*)&As[row][c] = ha;
            }
#pragma unroll
            for (int i = 0; i < 8; ++i) {
                const int idx = t + i * 256, row = idx >> 4, c = (idx & 15) * 4;
                bf16x4 hb;
#pragma unroll
                for (int e = 0; e < 4; ++e) hb[e] = (__bf16)pb[i][e];
                *(bf16x4*)&Bs[row][c] = hb;
            }
            __syncthreads();
            if (k0 + 64 < K) load(k0 + 64);
#pragma unroll
            for (int kc = 0; kc < 2; ++kc) {
                const int ko = kc * 32 + quad * 8;
                bf16x8 a[4], b[2];
#pragma unroll
                for (int i = 0; i < 4; ++i) a[i] = *(const bf16x8*)&As[i * 16 + m16][ko];
#pragma unroll
                for (int j = 0; j < 2; ++j) b[j] = *(const bf16x8*)&Bs[wc + j * 16 + m16][ko];
#pragma unroll
                for (int i = 0; i < 4; ++i)
#pragma unroll
                    for (int j = 0; j < 2; ++j)
                        acc[i][j] = __builtin_amdgcn_mfma_f32_16x16x32_bf16(a[i], b[j], acc[i][j], 0, 0, 0);
            }
        }
    }
#pragma unroll
    for (int i = 0; i < 4; ++i)
#pragma unroll
        for (int j = 0; j < 2; ++j)
#pragma unroll
            for (int r = 0; r < 4; ++r) {
                const int gm = m0 + i * 16 + quad * 4 + r;
                const int gn = n0 + wc + j * 16 + m16;
                Y[(size_t)gm * N + gn] = (__bf16)acc[i][j][r];
            }
}

// ---------------------------------------------------------------------------
__global__ __launch_bounds__(256) void zero_f32(float* __restrict__ p, int n)
{
    const int i = blockIdx.x * 256 + threadIdx.x;
    if (i < n) p[i] = 0.f;
}

// ---------------------------------------------------------------------------
// Channel QK v3 (MFMA): S[bh][i][j] = sum_n Qc[n][i]*Kc[n][j], 32 n-splits
// of 128. Contraction axis = tokens (strided) => stage Q^T/K^T in LDS:
// coalesced global row loads + ds_write_u16 transpose scatter into
// Qt[64ch][136] (stride 272B: writes ~8-way = ~3x free, cheap; b128 frag
// reads 16B-aligned, 2 lanes/slot = free). Wave w owns i-tile w; 16 MFMA.
// ATOMIC=1: atomics into S (legacy). ATOMIC=0: plain stores into
// Spart[bx][64][64]; chan_softmax<32> consumes splits directly.
// ---------------------------------------------------------------------------
template <int ATOMIC>
__global__ __launch_bounds__(256) void chan_qk(const __bf16* __restrict__ Qc,
                                               const __bf16* __restrict__ Kc,
                                               float* __restrict__ S)
{
    __shared__ __align__(16) __bf16 Qt[64][136];  // [channel][token] (Q^T)
    __shared__ __align__(16) __bf16 Kt[64][136];
    const int bx = blockIdx.x;
    const int bh = bx >> 5, split = bx & 31;
    const int b = bh >> 3, hh = bh & 7;
    const int n0 = split * 128;
    const int t = threadIdx.x;
    const size_t base = ((size_t)b * 4096 + (size_t)hh * 512) * 512;

    // Transpose-stage: 1024 row-chunks (128 tokens x 8 chunks), coalesced
    // global loads, scalar LDS scatter.
    for (int idx = t; idx < 1024; idx += 256) {
        const int row = idx >> 3, c0 = (idx & 7) * 8;  // token row, channel base
        bf16x8 q = *(const bf16x8*)(Qc + base + (size_t)(n0 + row) * 64 + c0);
        bf16x8 k = *(const bf16x8*)(Kc + base + (size_t)(n0 + row) * 64 + c0);
#pragma unroll
        for (int e = 0; e < 8; ++e) {
            Qt[c0 + e][row] = q[e];
            Kt[c0 + e][row] = k[e];
        }
    }
    __syncthreads();

    const int wave = t >> 6, lane = t & 63;
    const int m16 = lane & 15, quad = lane >> 4;

    f32x4 acc[4];
#pragma unroll
    for (int tj = 0; tj < 4; ++tj) acc[tj] = (f32x4){0.f, 0.f, 0.f, 0.f};

    // Wave owns i-tile = wave; loop j-tiles; K=128 in 4 steps of 32.
#pragma unroll
    for (int ks = 0; ks < 4; ++ks) {
        const int ko = ks * 32 + quad * 8;
        bf16x8 af = *(const bf16x8*)&Qt[wave * 16 + m16][ko];
#pragma unroll
        for (int tj = 0; tj < 4; ++tj) {
            bf16x8 bfr = *(const bf16x8*)&Kt[tj * 16 + m16][ko];
            acc[tj] = __builtin_amdgcn_mfma_f32_16x16x32_bf16(af, bfr, acc[tj], 0, 0, 0);
        }
    }

    // D layout: row i = wave*16 + quad*4 + r, col j = tj*16 + m16.
    if (ATOMIC) {
        float* Sb = S + (size_t)bh * 4096;
#pragma unroll
        for (int tj = 0; tj < 4; ++tj)
#pragma unroll
            for (int r = 0; r < 4; ++r)
                atomicAdd(&Sb[(wave * 16 + quad * 4 + r) * 64 + tj * 16 + m16], acc[tj][r]);
    } else {
        float* Sp = S + (size_t)bx * 4096;
#pragma unroll
        for (int tj = 0; tj < 4; ++tj)
#pragma unroll
            for (int r = 0; r < 4; ++r)
                Sp[(wave * 16 + quad * 4 + r) * 64 + tj * 16 + m16] = acc[tj][r];
    }
}

// ---------------------------------------------------------------------------
// Channel softmax v2: one WAVE per 64-elem row (1024 rows = 16bh x 64i);
// grid 256 x 256 threads. Lane j holds elem j: coalesced loads, shfl_xor
// max/sum. NSPLIT>1: fuses the qk split reduction (reads 32 partial tiles).
// ---------------------------------------------------------------------------
template <int NSPLIT>
__global__ __launch_bounds__(256) void chan_softmax(const float* __restrict__ S,
                                                    const void* __restrict__ temp,
                                                    __bf16* __restrict__ P,
                                                    const int* __restrict__ flag)
{
    const int row = blockIdx.x * 4 + (threadIdx.x >> 6);  // 0..1023
    const int bh = row >> 6, i = row & 63;
    const int hh = bh & 7;
    const int j = threadIdx.x & 63;
    const float tv = (*flag) ? (float)((const __bf16*)temp)[hh] : ((const float*)temp)[hh];
    const float scale = 0.125f * tv;

    float v;
    if (NSPLIT > 1) {
        const float* p = S + ((size_t)bh * NSPLIT) * 4096 + (size_t)i * 64 + j;
        float s = 0.f;
#pragma unroll
        for (int sp = 0; sp < NSPLIT; ++sp) s += p[(size_t)sp * 4096];
        v = s * scale;
    } else {
        v = S[(size_t)bh * 4096 + (size_t)i * 64 + j] * scale;
    }
    float mx = v;
#pragma unroll
    for (int d = 1; d < 64; d <<= 1) mx = fmaxf(mx, __shfl_xor(mx, d, 64));
    const float e = __builtin_amdgcn_exp2f((v - mx) * LOG2E);
    float sum = e;
#pragma unroll
    for (int d = 1; d < 64; d <<= 1) sum += __shfl_xor(sum, d, 64);
    P[(size_t)bh * 4096 + (size_t)i * 64 + j] = (__bf16)(e / sum);
}

// ---------------------------------------------------------------------------
// Channel AV v3 (MFMA + LDS-staged operands): x_ca[i][n] = sum_j P[i][j]*Vc[n][j].
// Per bh a 64x4096x64 GEMM. Block = (bh, 64-wide n chunk), 4 waves; wave
// owns i-tile (=wave), 4 n-tiles. P (8KB) and Vc tile (8KB) staged into LDS
// with row-contiguous coalesced bf16x8 loads. Frags from LDS [64][72]
// (2-way bank aliasing = free). D quad stores 16 contiguous fp32.
// out[b][h*512 + i*8 + n/512][n%512].
// ---------------------------------------------------------------------------
__global__ __launch_bounds__(256) void chan_av(const __bf16* __restrict__ P,
                                               const __bf16* __restrict__ Vc,
                                               void* __restrict__ out,
                                               const int* __restrict__ flag)
{
    __shared__ __align__(16) __bf16 Pl[64][72];
    __shared__ __align__(16) __bf16 Vl[64][72];
    const int bf = *flag;
    const int bx = blockIdx.x;
    const int bh = bx >> 6, ch = bx & 63;
    const int b = bh >> 3, hh = bh & 7;
    const int n0 = ch * 64;
    const int t = threadIdx.x, wave = t >> 6, lane = t & 63;
    const int m16 = lane & 15, quad = lane >> 4;
    const size_t base = ((size_t)b * 4096 + (size_t)hh * 512) * 512;  // Vc head slab
    const __bf16* Pb = P + (size_t)bh * 4096;

    // Coalesced staging: 512 bf16x8 chunks each for P and the Vc tile.
    {
        const int idx0 = t, row0 = idx0 >> 3, off0 = (idx0 & 7) * 8;
        const int idx1 = t + 256, row1 = idx1 >> 3, off1 = (idx1 & 7) * 8;
        *(bf16x8*)&Pl[row0][off0] = *(const bf16x8*)(Pb + (size_t)row0 * 64 + off0);
        *(bf16x8*)&Pl[row1][off1] = *(const bf16x8*)(Pb + (size_t)row1 * 64 + off1);
        *(bf16x8*)&Vl[row0][off0] = *(const bf16x8*)(Vc + base + (size_t)(n0 + row0) * 64 + off0);
        *(bf16x8*)&Vl[row1][off1] = *(const bf16x8*)(Vc + base + (size_t)(n0 + row1) * 64 + off1);
    }
    __syncthreads();

    // A-frags: P[i = wave*16 + m16][kc*32 + quad*8 .. +8]
    bf16x8 a[2];
#pragma unroll
    for (int kc = 0; kc < 2; ++kc)
        a[kc] = *(const bf16x8*)&Pl[wave * 16 + m16][kc * 32 + quad * 8];

    f32x4 acc[4];
#pragma unroll
    for (int nt = 0; nt < 4; ++nt) {
        acc[nt] = (f32x4){0.f, 0.f, 0.f, 0.f};
        bf16x8 bv[2];
#pragma unroll
        for (int kc = 0; kc < 2; ++kc)
            bv[kc] = *(const bf16x8*)&Vl[nt * 16 + m16][kc * 32 + quad * 8];
#pragma unroll
        for (int kc = 0; kc < 2; ++kc)
            acc[nt] = __builtin_amdgcn_mfma_f32_16x16x32_bf16(a[kc], bv[kc], acc[nt], 0, 0, 0);
    }

#pragma unroll
    for (int nt = 0; nt < 4; ++nt) {
        const int n = n0 + nt * 16 + m16;
#pragma unroll
        for (int r = 0; r < 4; ++r) {
            const int i = wave * 16 + quad * 4 + r;
            const size_t addr = (size_t)b * 2621440
                              + (size_t)(hh * 512 + i * 8 + (n >> 9)) * 640 + (n & 511);
            if (bf) ((__bf16*)out)[addr] = (__bf16)acc[nt][r];
            else    ((float*)out)[addr]  = acc[nt][r];
        }
    }
}

// ---------------------------------------------------------------------------
// Spatial flash attention v8 (R13-proven form): 512-thread blocks, 8 waves x
// 2 q-groups = 256 q-rows/block; gridDim.y = nsplit key-splits (additive
// combine). Double-buffered K/V LDS (V transposed at stage), one barrier/iter.
// PV in-register via 16x16x16 MFMA; denominator via ones-B MFMA.
// Operand-swap S^T = mfma(K,Q); Q pre-scaled.
// Output: out[b][h*512 + n/8][512 + (n%8)*16 + c].
// ---------------------------------------------------------------------------
template <int PATH>
__global__ __launch_bounds__(512) void flash_sa(const __bf16* __restrict__ Qs,
                                                const __bf16* __restrict__ Ks,
                                                const __bf16* __restrict__ Vs,
                                                const void* __restrict__ temp2,
                                                void* __restrict__ out,
                                                float* __restrict__ po,
                                                float* __restrict__ pl,
                                                const int* __restrict__ flag)
{
    __shared__ __align__(16) __bf16 Kl[2][64][72];
    __shared__ __align__(16) __bf16 Vt[2][16][72];     // V^T: [c][key]
    const int bf = *flag;
    const int bid = blockIdx.x;
    const int qt = bid & 15;            // 256-row q tile
    const int bh = bid >> 4;
    const int b = bh >> 3, hh = bh & 7;
    const int nspl = gridDim.y;
    const int spl  = blockIdx.y;
    const int nkt  = 64 / nspl;
    const int kt0  = spl * nkt;
    const int t = threadIdx.x, wave = t >> 6, lane = t & 63;
    const int m16 = lane & 15, quad = lane >> 4;
    const size_t base  = ((size_t)b * 4096 + (size_t)hh * 512) * 512;
    const size_t vbase = ((size_t)b * 4096 + (size_t)hh * 512) * 128;
    const float tv = bf ? (float)((const __bf16*)temp2)[hh] : ((const float*)temp2)[hh];
    const float sl = 0.125f * tv * LOG2E;

    // Q B-frags for 2 q-groups (lane m16 = qrow, k-contiguous), pre-scaled.
    bf16x8 qa[2][2];
#pragma unroll
    for (int g = 0; g < 2; ++g) {
        const int qrow = qt * 256 + g * 128 + wave * 16 + m16;
#pragma unroll
        for (int kc = 0; kc < 2; ++kc) {
            bf16x8 raw = *(const bf16x8*)(Qs + base + (size_t)qrow * 64 + kc * 32 + quad * 8);
#pragma unroll
            for (int e = 0; e < 8; ++e) qa[g][kc][e] = (__bf16)((float)raw[e] * sl);
        }
    }

    // Ones B-frag for denominator MFMA (row-sum of P).
    bf16x4 ones;
#pragma unroll
    for (int e = 0; e < 4; ++e) ones[e] = (__bf16)1.0f;

    // K/V prefetch registers. K: 512 chunks, 1 per thread. V: threads 0-255.
    const int krow = t >> 3, koff = (t & 7) * 8;
    const bool vact = t < 256;
    const int vrow = t & 63, vcq = (t >> 6) & 3;  // V: b64/thread, c = vcq*4..+4
    bf16x8 pk;
    bf16x4 pv;
    auto pref = [&](int kt) {
        pk = *(const bf16x8*)(Ks + base + (size_t)(kt * 64 + krow) * 64 + koff);
        if (vact) pv = *(const bf16x4*)(Vs + vbase + (size_t)(kt * 64 + vrow) * 16 + vcq * 4);
    };
    auto stage = [&](int bi) {
        *(bf16x8*)&Kl[bi][krow][koff] = pk;
        if (vact) {
#pragma unroll
            for (int e = 0; e < 4; ++e) Vt[bi][vcq * 4 + e][vrow] = pv[e];
        }
    };

    pref(kt0);
    stage(0);
    pref(kt0 + 1);
    __syncthreads();

    f32x4 o[2]  = {(f32x4){0.f, 0.f, 0.f, 0.f}, (f32x4){0.f, 0.f, 0.f, 0.f}};
    f32x4 o2[2] = {(f32x4){0.f, 0.f, 0.f, 0.f}, (f32x4){0.f, 0.f, 0.f, 0.f}};

    for (int kk = 0; kk < nkt; ++kk) {
        const int cur = kk & 1;

        // K/V fragments from current buffer (shared by both q-groups).
        bf16x8 kb[4][2];
        bf16x4 vb16[4];
#pragma unroll
        for (int ct = 0; ct < 4; ++ct)
#pragma unroll
            for (int kc = 0; kc < 2; ++kc)
                kb[ct][kc] = *(const bf16x8*)&Kl[cur][ct * 16 + m16][kc * 32 + quad * 8];
#pragma unroll
        for (int ct = 0; ct < 4; ++ct)
            vb16[ct] = *(const bf16x4*)&Vt[cur][m16][ct * 16 + quad * 4];

        // Stage tile kk+1 into the other buffer; prefetch tile kk+2.
        if (kk + 1 < nkt) stage(cur ^ 1);
        if (kk + 2 < nkt) pref(kt0 + kk + 2);

#pragma unroll
        for (int g = 0; g < 2; ++g) {
            // S^T tiles: D row = key-within-16 (quad*4+r), col = qrow (m16)
            f32x4 st[4];
#pragma unroll
            for (int ct = 0; ct < 4; ++ct) {
                st[ct] = (f32x4){0.f, 0.f, 0.f, 0.f};
#pragma unroll
                for (int kc = 0; kc < 2; ++kc)
                    st[ct] = __builtin_amdgcn_mfma_f32_16x16x32_bf16(kb[ct][kc], qa[g][kc], st[ct], 0, 0, 0);
            }
            // P = exp2(S^T) in-register: lane holds P[qrow=m16][key=ct*16+quad*4+r]
            // == x16-MFMA A-operand layout (row=m16, k=quad*4+e). PV + row-sum.
#pragma unroll
            for (int ct = 0; ct < 4; ++ct) {
                bf16x4 pe;
#pragma unroll
                for (int r = 0; r < 4; ++r)
                    pe[r] = (__bf16)__builtin_amdgcn_exp2f(st[ct][r]);
                o[g]  = mfma16(pe, vb16[ct], o[g]);
                o2[g] = mfma16(pe, ones,     o2[g]);
            }
        }
        __syncthreads();  // next buffer staged; current buffer reads done
    }

    // Guard for the inline-asm MFMA fallback (compiler-unknown latency).
    asm volatile("s_nop 7\n\ts_nop 7");

    if (nspl == 1) {
#pragma unroll
        for (int g = 0; g < 2; ++g) {
#pragma unroll
            for (int r = 0; r < 4; ++r) {
                const int n = qt * 256 + g * 128 + wave * 16 + quad * 4 + r;
                const float val = o[g][r] / o2[g][r];
                const size_t addr = (size_t)b * 2621440
                                  + (size_t)(hh * 512 + (n >> 3)) * 640 + 512 + (n & 7) * 16 + m16;
                if (bf) ((__bf16*)out)[addr] = (__bf16)val;
                else    ((float*)out)[addr]  = val;
            }
        }
    } else {
        // fp32 partials; lane (m16, quad) owns O[n=..+quad*4+r][c=m16].
#pragma unroll
        for (int g = 0; g < 2; ++g) {
#pragma unroll
            for (int r = 0; r < 4; ++r) {
                const int n = qt * 256 + g * 128 + wave * 16 + quad * 4 + r;
                const size_t rowi = ((size_t)spl * 16 + bh) * 4096 + n;
                po[rowi * 16 + m16] = o[g][r];
                if (m16 == 0) pl[rowi] = o2[g][r];  // replicated across cols
            }
        }
    }
}

// ---------------------------------------------------------------------------
// Combine split-K partials: out = (sum_spl po) / (sum_spl pl).
// One thread per (bh, n) row; writes 16 contiguous channels (vectorized).
// ---------------------------------------------------------------------------
__global__ __launch_bounds__(256) void flash_combine(const float* __restrict__ po,
                                                     const float* __restrict__ pl,
                                                     void* __restrict__ out,
                                                     const int* __restrict__ flag,
                                                     int nspl)
{
    const int bf = *flag;
    const int tid = blockIdx.x * 256 + threadIdx.x;  // 65536 rows
    const int bh = tid >> 12, n = tid & 4095;
    const int b = bh >> 3, hh = bh & 7;

    f32x4 acc[4];
#pragma unroll
    for (int q = 0; q < 4; ++q) acc[q] = (f32x4){0.f, 0.f, 0.f, 0.f};
    float l = 0.f;
    for (int sp = 0; sp < nspl; ++sp) {
        const size_t rowi = ((size_t)sp * 16 + bh) * 4096 + n;
        const f32x4* r = (const f32x4*)(po + rowi * 16);
#pragma unroll
        for (int q = 0; q < 4; ++q) {
            const f32x4 v = r[q];
#pragma unroll
            for (int e = 0; e < 4; ++e) acc[q][e] += v[e];
        }
        l += pl[rowi];
    }
    const float inv = 1.f / l;
    const size_t addr = (size_t)b * 2621440
                      + (size_t)(hh * 512 + (n >> 3)) * 640 + 512 + (n & 7) * 16;
    if (bf) {
#pragma unroll
        for (int q = 0; q < 2; ++q) {
            bf16x8 w;
#pragma unroll
            for (int e = 0; e < 8; ++e) w[e] = (__bf16)(acc[q * 2 + (e >> 2)][e & 3] * inv);
            *(bf16x8*)((__bf16*)out + addr + q * 8) = w;
        }
    } else {
#pragma unroll
        for (int q = 0; q < 4; ++q) {
            f32x4 w;
#pragma unroll
            for (int e = 0; e < 4; ++e) w[e] = acc[q][e] * inv;
            *(f32x4*)((float*)out + addr + q * 4) = w;
        }
    }
}

// ---------------------------------------------------------------------------
extern "C" void kernel_launch(void* const* d_in, const int* in_sizes, int n_in,
                              void* d_out, int out_size, void* d_ws, size_t ws_size,
                              hipStream_t stream)
{
    const void* s    = d_in[0];
    const void* h_   = d_in[1];
    const void* sh   = d_in[2];
    const void* t1   = d_in[3];
    const void* t2   = d_in[4];
    const void* Wq_c = d_in[5];
    const void* Wq_s = d_in[6];
    const void* Wk_c = d_in[7];
    const void* Wv_c = d_in[8];
    const void* Wk_s = d_in[9];
    const void* Wv_s = d_in[10];

    const dim3 blk(256);
    const size_t PROJ = 4194304;  // 8192*512 bf16 elements

    const size_t WIDE_BYTES = 5 * PROJ * 2 + 1048576 * 2 + 65536 * 4 + 65536 * 2 + 256;

    if (ws_size >= WIDE_BYTES) {
        // ---------------- wide path: one fused projection launch ----------
        __bf16* qc = (__bf16*)d_ws;
        __bf16* kc = qc + PROJ;
        __bf16* vc = kc + PROJ;
        __bf16* qs = vc + PROJ;
        __bf16* ks = qs + PROJ;
        __bf16* vs = ks + PROJ;            // 8192x128 row-major
        float*  Sb = (float*)(vs + 1048576);
        __bf16* Pb = (__bf16*)(Sb + 65536);
        int*  flag = (int*)(Pb + 65536);

        detect_dtype<<<dim3(1), dim3(64), 0, stream>>>((const unsigned*)t1, flag);

        ProjArgs pa{};
        const void* Xs[6] = {s, sh, sh, sh, sh, h_};
        const void* Ws[6] = {Wq_c, Wk_c, Wv_c, Wq_s, Wk_s, Wv_s};
        __bf16*     Ys[6] = {qc, kc, vc, qs, ks, vs};
        const int   Ks_[6] = {512, 512, 512, 512, 512, 128};
        const int   yt[6] = {4, 4, 4, 4, 4, 1};  // 128-wide N tiles
        pa.ng = 6;
        int ofs = 0;
        for (int g = 0; g < 6; ++g) {
            pa.X[g] = Xs[g]; pa.W[g] = Ws[g]; pa.Y[g] = Ys[g]; pa.K[g] = Ks_[g];
            pa.yofs[g] = ofs; ofs += yt[g];
        }
        pa.yofs[6] = ofs;  // 21

        proj_gemm<<<dim3(128, 21), blk, 0, stream>>>(pa, flag);

        zero_f32<<<dim3(256), blk, 0, stream>>>(Sb, 65536);
        chan_qk<1><<<dim3(512), blk, 0, stream>>>(qc, kc, Sb);
        chan_softmax<1><<<dim3(256), blk, 0, stream>>>(Sb, t1, Pb, flag);
        chan_av<<<dim3(1024), blk, 0, stream>>>(Pb, vc, d_out, flag);
        // split-K flash: partials live in dead qc/kc/vc region (25 MB,
        // consumed by chan_qk/chan_av which precede flash in-stream).
        float* po = (float*)qc;                  // 4*16*4096*16 f32 = 16.8 MB
        float* pl = po + 4ull * 1048576;         // 4*16*4096 f32
        flash_sa<0><<<dim3(256, 4), dim3(512), 0, stream>>>(qs, ks, vs, t2, d_out, po, pl, flag);
        flash_combine<<<dim3(256), blk, 0, stream>>>(po, pl, d_out, flag, 4);
    } else {
        // ---------------- fallback: proven sequential reuse ---------------
        __bf16* A  = (__bf16*)d_ws;        // q_c -> v_c -> k_s
        __bf16* Bf = A + PROJ;             // k_c -> q_s
        __bf16* D  = Bf + PROJ;            // v_s: 8192x128 row-major
        float*  Sb = (float*)(D + 1048576);
        __bf16* Pb = (__bf16*)(Sb + 65536);
        int*  flag = (int*)(Pb + 65536);

        detect_dtype<<<dim3(1), dim3(64), 0, stream>>>((const unsigned*)t1, flag);

        auto mk2 = [&](const void* X0, const void* W0, __bf16* Y0, int K0, int t0,
                       const void* X1, const void* W1, __bf16* Y1, int K1, int t1_) {
            ProjArgs p{};
            p.ng = 2;
            p.X[0] = X0; p.W[0] = W0; p.Y[0] = Y0; p.K[0] = K0;
            p.X[1] = X1; p.W[1] = W1; p.Y[1] = Y1; p.K[1] = K1;
            p.yofs[0] = 0; p.yofs[1] = t0; p.yofs[2] = t0 + t1_;
            return p;
        };

        // scratch region after the fixed fallback layout (time-shared:
        // chan_qk partials first, then flash split-K partials).
        const size_t fb_end = (size_t)((char*)(flag + 1) - (char*)d_ws);
        const size_t pofs = (fb_end + 255) & ~(size_t)255;
        const size_t per_split = (1048576 + 65536) * 4;  // flash po + pl bytes/split
        const size_t qk_bytes = 512ull * 4096 * 4;       // 8 MB split tiles
        int nspl = 1;
        if (ws_size >= pofs + 4 * per_split)      nspl = 4;
        else if (ws_size >= pofs + 2 * per_split) nspl = 2;
        const bool qk_part = (ws_size >= pofs + qk_bytes);
        float* scratch = (float*)((char*)d_ws + pofs);

        // tiles 128-wide N: 512-col gemm = 4 tiles, 128-col = 1; M-tiles 64.
        ProjArgs p1 = mk2(s,  Wq_c, A,  512, 4, sh, Wk_c, Bf, 512, 4);
        proj_gemm<<<dim3(128, 8), blk, 0, stream>>>(p1, flag);
        if (qk_part) {
            chan_qk<0><<<dim3(512), blk, 0, stream>>>(A, Bf, scratch);
            chan_softmax<32><<<dim3(256), blk, 0, stream>>>(scratch, t1, Pb, flag);
        } else {
            zero_f32<<<dim3(256), blk, 0, stream>>>(Sb, 65536);
            chan_qk<1><<<dim3(512), blk, 0, stream>>>(A, Bf, Sb);
            chan_softmax<1><<<dim3(256), blk, 0, stream>>>(Sb, t1, Pb, flag);
        }

        ProjArgs p2 = mk2(sh, Wv_c, A, 512, 4, sh, Wq_s, Bf, 512, 4);
        proj_gemm<<<dim3(128, 8), blk, 0, stream>>>(p2, flag);
        chan_av<<<dim3(1024), blk, 0, stream>>>(Pb, A, d_out, flag);

        ProjArgs p3 = mk2(sh, Wk_s, A, 512, 4, h_, Wv_s, D, 128, 1);
        proj_gemm<<<dim3(128, 5), blk, 0, stream>>>(p3, flag);

        float* po = scratch;
        float* pl = po + (size_t)nspl * 1048576;
        flash_sa<1><<<dim3(256, nspl), dim3(512), 0, stream>>>(Bf, A, D, t2, d_out, po, pl, flag);
        if (nspl > 1)
            flash_combine<<<dim3(256), blk, 0, stream>>>(po, pl, d_out, flag, nspl);
    }
}

// Round 13
// 217.022 us; speedup vs baseline: 1.0445x; 1.0445x over previous
//
#include <hip/hip_runtime.h>

// WCSA: B=2, N=4096, Cc=C=512, Cs=128, H=8, dc=d=64, ds=16.
// Internal compute: bf16 MFMA + fp32 accumulation. I/O dtype runtime-detected
// (fp32 confirmed; bf16 path kept).
//
// Head layout: reshape(B,N,C)->(B,H,N,d) direct => head h of a projection is
// the contiguous 512-row slab, row-major (4096,d).
//
// R20: R19 counters PROVED the WIDE path is live (one proj dispatch,
// WRITE_SIZE 43MB = all 6 outputs; R12's fallback inference was wrong).
//  (1) proj_gemm reverted to R18's 128x128 tile -- R19's 64x128 experiment
//      targeted fallback grids that never run; it doubled B re-reads and
//      regressed the live wide proj (e2e +4.3us). Falsified, reverted.
//  (2) Wide path wired to the atomic-free qk chain (chan_qk<0> +
//      chan_softmax<32>, zero_f32 dropped) -- it existed since R12/R14 but
//      only on the dead fallback branch. Gated on ws >= WIDE_BYTES + 8MB
//      (scratch appended after wide layout; legacy atomic chain kept).
// proj counters (R19): FETCH 85.6MB vs ~42 compulsory, 24% HBM, all pipes
// idle -> latency/over-fetch bound, ~2x above roofline = next target.
// flash = control (~66.5us).

typedef __attribute__((ext_vector_type(8))) __bf16 bf16x8;
typedef __attribute__((ext_vector_type(4))) __bf16 bf16x4;
typedef __attribute__((ext_vector_type(4))) float  f32x4;
typedef __attribute__((ext_vector_type(4))) short  s16x4;

#define LOG2E 1.44269504088896340736f

// 16x16x16 bf16 MFMA: A/B = 4 bf16 (2 VGPRs), C/D = 4 f32.
static __device__ __forceinline__ f32x4 mfma16(bf16x4 a, bf16x4 b, f32x4 c)
{
#if __has_builtin(__builtin_amdgcn_mfma_f32_16x16x16bf16_1k)
    union { bf16x4 h; s16x4 s; } ua, ub;
    ua.h = a; ub.h = b;
    return __builtin_amdgcn_mfma_f32_16x16x16bf16_1k(ua.s, ub.s, c, 0, 0, 0);
#elif __has_builtin(__builtin_amdgcn_mfma_f32_16x16x16_bf16)
    return __builtin_amdgcn_mfma_f32_16x16x16_bf16(a, b, c, 0, 0, 0);
#else
    asm("v_mfma_f32_16x16x16_bf16 %0, %1, %2, %0" : "+v"(c) : "v"(a), "v"(b));
    return c;
#endif
}

// ---------------------------------------------------------------------------
__global__ void detect_dtype(const unsigned* __restrict__ temp, int* __restrict__ flag)
{
    if (threadIdx.x == 0) {
        const unsigned w = temp[0];
        flag[0] = ((w >> 16) == (w & 0xffffu)) ? 1 : 0;  // 1 = bf16 I/O
    }
}

// ---------------------------------------------------------------------------
// Fused projection GEMMs, 128(M)x128(N) tile, BK=64, register prefetch.
// 4 waves in 2(M)x2(N); wave tile 64x64 = 4x4 of 16x16x32 MFMA (32 MFMA/iter).
// blockIdx.y -> group via prefix table in units of 128-wide N-tiles.
// LDS row stride 72 bf16.
// ---------------------------------------------------------------------------
struct ProjArgs {
    const void* X[6];
    const void* W[6];
    __bf16*     Y[6];
    int         K[6];
    int         yofs[7];  // units of 128-wide N tiles
    int         ng;
};

__global__ __launch_bounds__(256) void proj_gemm(ProjArgs args,
                                                 const int* __restrict__ flag)
{
    __shared__ __align__(16) __bf16 As[128][72];
    __shared__ __align__(16) __bf16 Bs[128][72];
    const int bf = *flag;
    const int by = blockIdx.y;
    int g = 0;
    while (by >= args.yofs[g + 1]) ++g;  // <=6 iters, wave-uniform
    const int n0 = (by - args.yofs[g]) * 128;
    const int N  = (args.yofs[g + 1] - args.yofs[g]) * 128;
    const int K  = args.K[g];
    const void* X = args.X[g];
    const void* W = args.W[g];
    __bf16*     Y = args.Y[g];

    const int m0 = blockIdx.x * 128;
    const int t = threadIdx.x;
    const int wave = t >> 6, lane = t & 63;
    const int wr = (wave >> 1) * 64, wc = (wave & 1) * 64;
    const int m16 = lane & 15, quad = lane >> 4;

    f32x4 acc[4][4];
#pragma unroll
    for (int i = 0; i < 4; ++i)
#pragma unroll
        for (int j = 0; j < 4; ++j) acc[i][j] = (f32x4){0.f, 0.f, 0.f, 0.f};

    if (bf) {
        // ---- bf16 inputs: prefetch A 4x + B 4x bf16x8 ----
        const __bf16* Xb = (const __bf16*)X;
        const __bf16* Wb = (const __bf16*)W;
        bf16x8 pa[4], pb[4];
        auto load = [&](int k0) {
#pragma unroll
            for (int i = 0; i < 4; ++i) {
                const int idx = t + i * 256, row = idx >> 3, off = (idx & 7) * 8;
                pa[i] = *(const bf16x8*)(Xb + (size_t)(m0 + row) * K + k0 + off);
            }
#pragma unroll
            for (int i = 0; i < 4; ++i) {
                const int idx = t + i * 256, row = idx >> 3, off = (idx & 7) * 8;
                pb[i] = *(const bf16x8*)(Wb + (size_t)(n0 + row) * K + k0 + off);
            }
        };
        load(0);
        for (int k0 = 0; k0 < K; k0 += 64) {
            __syncthreads();
#pragma unroll
            for (int i = 0; i < 4; ++i) {
                const int idx = t + i * 256, row = idx >> 3, off = (idx & 7) * 8;
                *(bf16x8*)&As[row][off] = pa[i];
            }
#pragma unroll
            for (int i = 0; i < 4; ++i) {
                const int idx = t + i * 256, row = idx >> 3, off = (idx & 7) * 8;
                *(bf16x8*)&Bs[row][off] = pb[i];
            }
            __syncthreads();
            if (k0 + 64 < K) load(k0 + 64);
#pragma unroll
            for (int kc = 0; kc < 2; ++kc) {
                const int ko = kc * 32 + quad * 8;
                bf16x8 a[4], b[4];
#pragma unroll
                for (int i = 0; i < 4; ++i) a[i] = *(const bf16x8*)&As[wr + i * 16 + m16][ko];
#pragma unroll
                for (int j = 0; j < 4; ++j) b[j] = *(const bf16x8*)&Bs[wc + j * 16 + m16][ko];
#pragma unroll
                for (int i = 0; i < 4; ++i)
#pragma unroll
                    for (int j = 0; j < 4; ++j)
                        acc[i][j] = __builtin_amdgcn_mfma_f32_16x16x32_bf16(a[i], b[j], acc[i][j], 0, 0, 0);
            }
        }
    } else {
        // ---- fp32 inputs: prefetch A 8x + B 8x f32x4 (cvt at store) ----
        const float* Xf = (const float*)X;
        const float* Wf = (const float*)W;
        f32x4 pa[8], pb[8];
        auto load = [&](int k0) {
#pragma unroll
            for (int i = 0; i < 8; ++i) {
                const int idx = t + i * 256, row = idx >> 4, c = (idx & 15) * 4;
                pa[i] = *(const f32x4*)(Xf + (size_t)(m0 + row) * K + k0 + c);
            }
#pragma unroll
            for (int i = 0; i < 8; ++i) {
                const int idx = t + i * 256, row = idx >> 4, c = (idx & 15) * 4;
                pb[i] = *(const f32x4*)(Wf + (size_t)(n0 + row) * K + k0 + c);
            }
        };
        load(0);
        for (int k0 = 0; k0 < K; k0 += 64) {
            __syncthreads();
#pragma unroll
            for (int i = 0; i < 8; ++i) {
                const int idx = t + i * 256, row = idx >> 4, c = (idx & 15) * 4;
                bf16x4 ha;
#pragma unroll
                for (int e = 0; e < 4; ++e) ha[e] = (__bf16)pa[i][e];
                *(bf16x4*)&As[row][c] = ha;
            }
#pragma unroll
            for (int i = 0; i < 8; ++i) {
                const int idx = t + i * 256, row = idx >> 4, c = (idx & 15) * 4;
                bf16x4 hb;
#pragma unroll
                for (int e = 0; e < 4; ++e) hb[e] = (__bf16)pb[i][e];
                *(bf16x4*)&Bs[row][c] = hb;
            }
            __syncthreads();
            if (k0 + 64 < K) load(k0 + 64);
#pragma unroll
            for (int kc = 0; kc < 2; ++kc) {
                const int ko = kc * 32 + quad * 8;
                bf16x8 a[4], b[4];
#pragma unroll
                for (int i = 0; i < 4; ++i) a[i] = *(const bf16x8*)&As[wr + i * 16 + m16][ko];
#pragma unroll
                for (int j = 0; j < 4; ++j) b[j] = *(const bf16x8*)&Bs[wc + j * 16 + m16][ko];
#pragma unroll
                for (int i = 0; i < 4; ++i)
#pragma unroll
                    for (int j = 0; j < 4; ++j)
                        acc[i][j] = __builtin_amdgcn_mfma_f32_16x16x32_bf16(a[i], b[j], acc[i][j], 0, 0, 0);
            }
        }
    }
#pragma unroll
    for (int i = 0; i < 4; ++i)
#pragma unroll
        for (int j = 0; j < 4; ++j)
#pragma unroll
            for (int r = 0; r < 4; ++r) {
                const int gm = m0 + wr + i * 16 + quad * 4 + r;
                const int gn = n0 + wc + j * 16 + m16;
                Y[(size_t)gm * N + gn] = (__bf16)acc[i][j][r];
            }
}

// ---------------------------------------------------------------------------
__global__ __launch_bounds__(256) void zero_f32(float* __restrict__ p, int n)
{
    const int i = blockIdx.x * 256 + threadIdx.x;
    if (i < n) p[i] = 0.f;
}

// ---------------------------------------------------------------------------
// Channel QK v3 (MFMA): S[bh][i][j] = sum_n Qc[n][i]*Kc[n][j], 32 n-splits
// of 128. Contraction axis = tokens (strided) => stage Q^T/K^T in LDS:
// coalesced global row loads + ds_write_u16 transpose scatter into
// Qt[64ch][136]. Wave w owns i-tile w; 16 MFMA.
// ATOMIC=1: atomics into S (legacy). ATOMIC=0: plain stores into
// Spart[bx][64][64]; chan_softmax<32> consumes splits directly.
// ---------------------------------------------------------------------------
template <int ATOMIC>
__global__ __launch_bounds__(256) void chan_qk(const __bf16* __restrict__ Qc,
                                               const __bf16* __restrict__ Kc,
                                               float* __restrict__ S)
{
    __shared__ __align__(16) __bf16 Qt[64][136];  // [channel][token] (Q^T)
    __shared__ __align__(16) __bf16 Kt[64][136];
    const int bx = blockIdx.x;
    const int bh = bx >> 5, split = bx & 31;
    const int b = bh >> 3, hh = bh & 7;
    const int n0 = split * 128;
    const int t = threadIdx.x;
    const size_t base = ((size_t)b * 4096 + (size_t)hh * 512) * 512;

    // Transpose-stage: 1024 row-chunks (128 tokens x 8 chunks), coalesced
    // global loads, scalar LDS scatter.
    for (int idx = t; idx < 1024; idx += 256) {
        const int row = idx >> 3, c0 = (idx & 7) * 8;  // token row, channel base
        bf16x8 q = *(const bf16x8*)(Qc + base + (size_t)(n0 + row) * 64 + c0);
        bf16x8 k = *(const bf16x8*)(Kc + base + (size_t)(n0 + row) * 64 + c0);
#pragma unroll
        for (int e = 0; e < 8; ++e) {
            Qt[c0 + e][row] = q[e];
            Kt[c0 + e][row] = k[e];
        }
    }
    __syncthreads();

    const int wave = t >> 6, lane = t & 63;
    const int m16 = lane & 15, quad = lane >> 4;

    f32x4 acc[4];
#pragma unroll
    for (int tj = 0; tj < 4; ++tj) acc[tj] = (f32x4){0.f, 0.f, 0.f, 0.f};

    // Wave owns i-tile = wave; loop j-tiles; K=128 in 4 steps of 32.
#pragma unroll
    for (int ks = 0; ks < 4; ++ks) {
        const int ko = ks * 32 + quad * 8;
        bf16x8 af = *(const bf16x8*)&Qt[wave * 16 + m16][ko];
#pragma unroll
        for (int tj = 0; tj < 4; ++tj) {
            bf16x8 bfr = *(const bf16x8*)&Kt[tj * 16 + m16][ko];
            acc[tj] = __builtin_amdgcn_mfma_f32_16x16x32_bf16(af, bfr, acc[tj], 0, 0, 0);
        }
    }

    // D layout: row i = wave*16 + quad*4 + r, col j = tj*16 + m16.
    if (ATOMIC) {
        float* Sb = S + (size_t)bh * 4096;
#pragma unroll
        for (int tj = 0; tj < 4; ++tj)
#pragma unroll
            for (int r = 0; r < 4; ++r)
                atomicAdd(&Sb[(wave * 16 + quad * 4 + r) * 64 + tj * 16 + m16], acc[tj][r]);
    } else {
        float* Sp = S + (size_t)bx * 4096;
#pragma unroll
        for (int tj = 0; tj < 4; ++tj)
#pragma unroll
            for (int r = 0; r < 4; ++r)
                Sp[(wave * 16 + quad * 4 + r) * 64 + tj * 16 + m16] = acc[tj][r];
    }
}

// ---------------------------------------------------------------------------
// Channel softmax v2: one WAVE per 64-elem row (1024 rows = 16bh x 64i);
// grid 256 x 256 threads. Lane j holds elem j: coalesced loads, shfl_xor
// max/sum. NSPLIT>1: fuses the qk split reduction (reads 32 partial tiles).
// ---------------------------------------------------------------------------
template <int NSPLIT>
__global__ __launch_bounds__(256) void chan_softmax(const float* __restrict__ S,
                                                    const void* __restrict__ temp,
                                                    __bf16* __restrict__ P,
                                                    const int* __restrict__ flag)
{
    const int row = blockIdx.x * 4 + (threadIdx.x >> 6);  // 0..1023
    const int bh = row >> 6, i = row & 63;
    const int hh = bh & 7;
    const int j = threadIdx.x & 63;
    const float tv = (*flag) ? (float)((const __bf16*)temp)[hh] : ((const float*)temp)[hh];
    const float scale = 0.125f * tv;

    float v;
    if (NSPLIT > 1) {
        const float* p = S + ((size_t)bh * NSPLIT) * 4096 + (size_t)i * 64 + j;
        float s = 0.f;
#pragma unroll
        for (int sp = 0; sp < NSPLIT; ++sp) s += p[(size_t)sp * 4096];
        v = s * scale;
    } else {
        v = S[(size_t)bh * 4096 + (size_t)i * 64 + j] * scale;
    }
    float mx = v;
#pragma unroll
    for (int d = 1; d < 64; d <<= 1) mx = fmaxf(mx, __shfl_xor(mx, d, 64));
    const float e = __builtin_amdgcn_exp2f((v - mx) * LOG2E);
    float sum = e;
#pragma unroll
    for (int d = 1; d < 64; d <<= 1) sum += __shfl_xor(sum, d, 64);
    P[(size_t)bh * 4096 + (size_t)i * 64 + j] = (__bf16)(e / sum);
}

// ---------------------------------------------------------------------------
// Channel AV v3 (MFMA + LDS-staged operands): x_ca[i][n] = sum_j P[i][j]*Vc[n][j].
// Per bh a 64x4096x64 GEMM. Block = (bh, 64-wide n chunk), 4 waves; wave
// owns i-tile (=wave), 4 n-tiles. P (8KB) and Vc tile (8KB) staged into LDS
// with row-contiguous coalesced bf16x8 loads. Frags from LDS [64][72]
// (2-way bank aliasing = free). D quad stores 16 contiguous fp32.
// out[b][h*512 + i*8 + n/512][n%512].
// ---------------------------------------------------------------------------
__global__ __launch_bounds__(256) void chan_av(const __bf16* __restrict__ P,
                                               const __bf16* __restrict__ Vc,
                                               void* __restrict__ out,
                                               const int* __restrict__ flag)
{
    __shared__ __align__(16) __bf16 Pl[64][72];
    __shared__ __align__(16) __bf16 Vl[64][72];
    const int bf = *flag;
    const int bx = blockIdx.x;
    const int bh = bx >> 6, ch = bx & 63;
    const int b = bh >> 3, hh = bh & 7;
    const int n0 = ch * 64;
    const int t = threadIdx.x, wave = t >> 6, lane = t & 63;
    const int m16 = lane & 15, quad = lane >> 4;
    const size_t base = ((size_t)b * 4096 + (size_t)hh * 512) * 512;  // Vc head slab
    const __bf16* Pb = P + (size_t)bh * 4096;

    // Coalesced staging: 512 bf16x8 chunks each for P and the Vc tile.
    {
        const int idx0 = t, row0 = idx0 >> 3, off0 = (idx0 & 7) * 8;
        const int idx1 = t + 256, row1 = idx1 >> 3, off1 = (idx1 & 7) * 8;
        *(bf16x8*)&Pl[row0][off0] = *(const bf16x8*)(Pb + (size_t)row0 * 64 + off0);
        *(bf16x8*)&Pl[row1][off1] = *(const bf16x8*)(Pb + (size_t)row1 * 64 + off1);
        *(bf16x8*)&Vl[row0][off0] = *(const bf16x8*)(Vc + base + (size_t)(n0 + row0) * 64 + off0);
        *(bf16x8*)&Vl[row1][off1] = *(const bf16x8*)(Vc + base + (size_t)(n0 + row1) * 64 + off1);
    }
    __syncthreads();

    // A-frags: P[i = wave*16 + m16][kc*32 + quad*8 .. +8]
    bf16x8 a[2];
#pragma unroll
    for (int kc = 0; kc < 2; ++kc)
        a[kc] = *(const bf16x8*)&Pl[wave * 16 + m16][kc * 32 + quad * 8];

    f32x4 acc[4];
#pragma unroll
    for (int nt = 0; nt < 4; ++nt) {
        acc[nt] = (f32x4){0.f, 0.f, 0.f, 0.f};
        bf16x8 bv[2];
#pragma unroll
        for (int kc = 0; kc < 2; ++kc)
            bv[kc] = *(const bf16x8*)&Vl[nt * 16 + m16][kc * 32 + quad * 8];
#pragma unroll
        for (int kc = 0; kc < 2; ++kc)
            acc[nt] = __builtin_amdgcn_mfma_f32_16x16x32_bf16(a[kc], bv[kc], acc[nt], 0, 0, 0);
    }

#pragma unroll
    for (int nt = 0; nt < 4; ++nt) {
        const int n = n0 + nt * 16 + m16;
#pragma unroll
        for (int r = 0; r < 4; ++r) {
            const int i = wave * 16 + quad * 4 + r;
            const size_t addr = (size_t)b * 2621440
                              + (size_t)(hh * 512 + i * 8 + (n >> 9)) * 640 + (n & 511);
            if (bf) ((__bf16*)out)[addr] = (__bf16)acc[nt][r];
            else    ((float*)out)[addr]  = acc[nt][r];
        }
    }
}

// ---------------------------------------------------------------------------
// Spatial flash attention v8 (R13-proven form): 512-thread blocks, 8 waves x
// 2 q-groups = 256 q-rows/block; gridDim.y = nsplit key-splits (additive
// combine). Double-buffered K/V LDS (V transposed at stage), one barrier/iter.
// PV in-register via 16x16x16 MFMA; denominator via ones-B MFMA.
// Operand-swap S^T = mfma(K,Q); Q pre-scaled.
// Output: out[b][h*512 + n/8][512 + (n%8)*16 + c].
// ---------------------------------------------------------------------------
template <int PATH>
__global__ __launch_bounds__(512) void flash_sa(const __bf16* __restrict__ Qs,
                                                const __bf16* __restrict__ Ks,
                                                const __bf16* __restrict__ Vs,
                                                const void* __restrict__ temp2,
                                                void* __restrict__ out,
                                                float* __restrict__ po,
                                                float* __restrict__ pl,
                                                const int* __restrict__ flag)
{
    __shared__ __align__(16) __bf16 Kl[2][64][72];
    __shared__ __align__(16) __bf16 Vt[2][16][72];     // V^T: [c][key]
    const int bf = *flag;
    const int bid = blockIdx.x;
    const int qt = bid & 15;            // 256-row q tile
    const int bh = bid >> 4;
    const int b = bh >> 3, hh = bh & 7;
    const int nspl = gridDim.y;
    const int spl  = blockIdx.y;
    const int nkt  = 64 / nspl;
    const int kt0  = spl * nkt;
    const int t = threadIdx.x, wave = t >> 6, lane = t & 63;
    const int m16 = lane & 15, quad = lane >> 4;
    const size_t base  = ((size_t)b * 4096 + (size_t)hh * 512) * 512;
    const size_t vbase = ((size_t)b * 4096 + (size_t)hh * 512) * 128;
    const float tv = bf ? (float)((const __bf16*)temp2)[hh] : ((const float*)temp2)[hh];
    const float sl = 0.125f * tv * LOG2E;

    // Q B-frags for 2 q-groups (lane m16 = qrow, k-contiguous), pre-scaled.
    bf16x8 qa[2][2];
#pragma unroll
    for (int g = 0; g < 2; ++g) {
        const int qrow = qt * 256 + g * 128 + wave * 16 + m16;
#pragma unroll
        for (int kc = 0; kc < 2; ++kc) {
            bf16x8 raw = *(const bf16x8*)(Qs + base + (size_t)qrow * 64 + kc * 32 + quad * 8);
#pragma unroll
            for (int e = 0; e < 8; ++e) qa[g][kc][e] = (__bf16)((float)raw[e] * sl);
        }
    }

    // Ones B-frag for denominator MFMA (row-sum of P).
    bf16x4 ones;
#pragma unroll
    for (int e = 0; e < 4; ++e) ones[e] = (__bf16)1.0f;

    // K/V prefetch registers. K: 512 chunks, 1 per thread. V: threads 0-255.
    const int krow = t >> 3, koff = (t & 7) * 8;
    const bool vact = t < 256;
    const int vrow = t & 63, vcq = (t >> 6) & 3;  // V: b64/thread, c = vcq*4..+4
    bf16x8 pk;
    bf16x4 pv;
    auto pref = [&](int kt) {
        pk = *(const bf16x8*)(Ks + base + (size_t)(kt * 64 + krow) * 64 + koff);
        if (vact) pv = *(const bf16x4*)(Vs + vbase + (size_t)(kt * 64 + vrow) * 16 + vcq * 4);
    };
    auto stage = [&](int bi) {
        *(bf16x8*)&Kl[bi][krow][koff] = pk;
        if (vact) {
#pragma unroll
            for (int e = 0; e < 4; ++e) Vt[bi][vcq * 4 + e][vrow] = pv[e];
        }
    };

    pref(kt0);
    stage(0);
    pref(kt0 + 1);
    __syncthreads();

    f32x4 o[2]  = {(f32x4){0.f, 0.f, 0.f, 0.f}, (f32x4){0.f, 0.f, 0.f, 0.f}};
    f32x4 o2[2] = {(f32x4){0.f, 0.f, 0.f, 0.f}, (f32x4){0.f, 0.f, 0.f, 0.f}};

    for (int kk = 0; kk < nkt; ++kk) {
        const int cur = kk & 1;

        // K/V fragments from current buffer (shared by both q-groups).
        bf16x8 kb[4][2];
        bf16x4 vb16[4];
#pragma unroll
        for (int ct = 0; ct < 4; ++ct)
#pragma unroll
            for (int kc = 0; kc < 2; ++kc)
                kb[ct][kc] = *(const bf16x8*)&Kl[cur][ct * 16 + m16][kc * 32 + quad * 8];
#pragma unroll
        for (int ct = 0; ct < 4; ++ct)
            vb16[ct] = *(const bf16x4*)&Vt[cur][m16][ct * 16 + quad * 4];

        // Stage tile kk+1 into the other buffer; prefetch tile kk+2.
        if (kk + 1 < nkt) stage(cur ^ 1);
        if (kk + 2 < nkt) pref(kt0 + kk + 2);

#pragma unroll
        for (int g = 0; g < 2; ++g) {
            // S^T tiles: D row = key-within-16 (quad*4+r), col = qrow (m16)
            f32x4 st[4];
#pragma unroll
            for (int ct = 0; ct < 4; ++ct) {
                st[ct] = (f32x4){0.f, 0.f, 0.f, 0.f};
#pragma unroll
                for (int kc = 0; kc < 2; ++kc)
                    st[ct] = __builtin_amdgcn_mfma_f32_16x16x32_bf16(kb[ct][kc], qa[g][kc], st[ct], 0, 0, 0);
            }
            // P = exp2(S^T) in-register: lane holds P[qrow=m16][key=ct*16+quad*4+r]
            // == x16-MFMA A-operand layout (row=m16, k=quad*4+e). PV + row-sum.
#pragma unroll
            for (int ct = 0; ct < 4; ++ct) {
                bf16x4 pe;
#pragma unroll
                for (int r = 0; r < 4; ++r)
                    pe[r] = (__bf16)__builtin_amdgcn_exp2f(st[ct][r]);
                o[g]  = mfma16(pe, vb16[ct], o[g]);
                o2[g] = mfma16(pe, ones,     o2[g]);
            }
        }
        __syncthreads();  // next buffer staged; current buffer reads done
    }

    // Guard for the inline-asm MFMA fallback (compiler-unknown latency).
    asm volatile("s_nop 7\n\ts_nop 7");

    if (nspl == 1) {
#pragma unroll
        for (int g = 0; g < 2; ++g) {
#pragma unroll
            for (int r = 0; r < 4; ++r) {
                const int n = qt * 256 + g * 128 + wave * 16 + quad * 4 + r;
                const float val = o[g][r] / o2[g][r];
                const size_t addr = (size_t)b * 2621440
                                  + (size_t)(hh * 512 + (n >> 3)) * 640 + 512 + (n & 7) * 16 + m16;
                if (bf) ((__bf16*)out)[addr] = (__bf16)val;
                else    ((float*)out)[addr]  = val;
            }
        }
    } else {
        // fp32 partials; lane (m16, quad) owns O[n=..+quad*4+r][c=m16].
#pragma unroll
        for (int g = 0; g < 2; ++g) {
#pragma unroll
            for (int r = 0; r < 4; ++r) {
                const int n = qt * 256 + g * 128 + wave * 16 + quad * 4 + r;
                const size_t rowi = ((size_t)spl * 16 + bh) * 4096 + n;
                po[rowi * 16 + m16] = o[g][r];
                if (m16 == 0) pl[rowi] = o2[g][r];  // replicated across cols
            }
        }
    }
}

// ---------------------------------------------------------------------------
// Combine split-K partials: out = (sum_spl po) / (sum_spl pl).
// One thread per (bh, n) row; writes 16 contiguous channels (vectorized).
// ---------------------------------------------------------------------------
__global__ __launch_bounds__(256) void flash_combine(const float* __restrict__ po,
                                                     const float* __restrict__ pl,
                                                     void* __restrict__ out,
                                                     const int* __restrict__ flag,
                                                     int nspl)
{
    const int bf = *flag;
    const int tid = blockIdx.x * 256 + threadIdx.x;  // 65536 rows
    const int bh = tid >> 12, n = tid & 4095;
    const int b = bh >> 3, hh = bh & 7;

    f32x4 acc[4];
#pragma unroll
    for (int q = 0; q < 4; ++q) acc[q] = (f32x4){0.f, 0.f, 0.f, 0.f};
    float l = 0.f;
    for (int sp = 0; sp < nspl; ++sp) {
        const size_t rowi = ((size_t)sp * 16 + bh) * 4096 + n;
        const f32x4* r = (const f32x4*)(po + rowi * 16);
#pragma unroll
        for (int q = 0; q < 4; ++q) {
            const f32x4 v = r[q];
#pragma unroll
            for (int e = 0; e < 4; ++e) acc[q][e] += v[e];
        }
        l += pl[rowi];
    }
    const float inv = 1.f / l;
    const size_t addr = (size_t)b * 2621440
                      + (size_t)(hh * 512 + (n >> 3)) * 640 + 512 + (n & 7) * 16;
    if (bf) {
#pragma unroll
        for (int q = 0; q < 2; ++q) {
            bf16x8 w;
#pragma unroll
            for (int e = 0; e < 8; ++e) w[e] = (__bf16)(acc[q * 2 + (e >> 2)][e & 3] * inv);
            *(bf16x8*)((__bf16*)out + addr + q * 8) = w;
        }
    } else {
#pragma unroll
        for (int q = 0; q < 4; ++q) {
            f32x4 w;
#pragma unroll
            for (int e = 0; e < 4; ++e) w[e] = acc[q][e] * inv;
            *(f32x4*)((float*)out + addr + q * 4) = w;
        }
    }
}

// ---------------------------------------------------------------------------
extern "C" void kernel_launch(void* const* d_in, const int* in_sizes, int n_in,
                              void* d_out, int out_size, void* d_ws, size_t ws_size,
                              hipStream_t stream)
{
    const void* s    = d_in[0];
    const void* h_   = d_in[1];
    const void* sh   = d_in[2];
    const void* t1   = d_in[3];
    const void* t2   = d_in[4];
    const void* Wq_c = d_in[5];
    const void* Wq_s = d_in[6];
    const void* Wk_c = d_in[7];
    const void* Wv_c = d_in[8];
    const void* Wk_s = d_in[9];
    const void* Wv_s = d_in[10];

    const dim3 blk(256);
    const size_t PROJ = 4194304;  // 8192*512 bf16 elements

    const size_t WIDE_BYTES = 5 * PROJ * 2 + 1048576 * 2 + 65536 * 4 + 65536 * 2 + 256;
    const size_t QK_BYTES = 512ull * 4096 * 4;  // 8 MB atomic-free qk partials

    if (ws_size >= WIDE_BYTES) {
        // ---------------- wide path (CONFIRMED LIVE, R19 counters) --------
        __bf16* qc = (__bf16*)d_ws;
        __bf16* kc = qc + PROJ;
        __bf16* vc = kc + PROJ;
        __bf16* qs = vc + PROJ;
        __bf16* ks = qs + PROJ;
        __bf16* vs = ks + PROJ;            // 8192x128 row-major
        float*  Sb = (float*)(vs + 1048576);
        __bf16* Pb = (__bf16*)(Sb + 65536);
        int*  flag = (int*)(Pb + 65536);

        detect_dtype<<<dim3(1), dim3(64), 0, stream>>>((const unsigned*)t1, flag);

        ProjArgs pa{};
        const void* Xs[6] = {s, sh, sh, sh, sh, h_};
        const void* Ws[6] = {Wq_c, Wk_c, Wv_c, Wq_s, Wk_s, Wv_s};
        __bf16*     Ys[6] = {qc, kc, vc, qs, ks, vs};
        const int   Ks_[6] = {512, 512, 512, 512, 512, 128};
        const int   yt[6] = {4, 4, 4, 4, 4, 1};  // 128-wide N tiles
        pa.ng = 6;
        int ofs = 0;
        for (int g = 0; g < 6; ++g) {
            pa.X[g] = Xs[g]; pa.W[g] = Ws[g]; pa.Y[g] = Ys[g]; pa.K[g] = Ks_[g];
            pa.yofs[g] = ofs; ofs += yt[g];
        }
        pa.yofs[6] = ofs;  // 21

        proj_gemm<<<dim3(64, 21), blk, 0, stream>>>(pa, flag);

        // Atomic-free qk chain if workspace has 8 MB beyond the wide layout
        // (scratch can't alias anything: chan_qk reads qc/kc, and qs/ks/vs/
        // vc/Sb/Pb are all still live at this point).
        if (ws_size >= WIDE_BYTES + QK_BYTES) {
            float* qkscr = (float*)((char*)d_ws + WIDE_BYTES);
            chan_qk<0><<<dim3(512), blk, 0, stream>>>(qc, kc, qkscr);
            chan_softmax<32><<<dim3(256), blk, 0, stream>>>(qkscr, t1, Pb, flag);
        } else {
            zero_f32<<<dim3(256), blk, 0, stream>>>(Sb, 65536);
            chan_qk<1><<<dim3(512), blk, 0, stream>>>(qc, kc, Sb);
            chan_softmax<1><<<dim3(256), blk, 0, stream>>>(Sb, t1, Pb, flag);
        }
        chan_av<<<dim3(1024), blk, 0, stream>>>(Pb, vc, d_out, flag);
        // split-K flash: partials live in dead qc/kc/vc region (25 MB,
        // consumed by chan_qk/chan_av which precede flash in-stream).
        float* po = (float*)qc;                  // 4*16*4096*16 f32 = 16.8 MB
        float* pl = po + 4ull * 1048576;         // 4*16*4096 f32
        flash_sa<0><<<dim3(256, 4), dim3(512), 0, stream>>>(qs, ks, vs, t2, d_out, po, pl, flag);
        flash_combine<<<dim3(256), blk, 0, stream>>>(po, pl, d_out, flag, 4);
    } else {
        // ---------------- fallback: sequential reuse (not the live path) --
        __bf16* A  = (__bf16*)d_ws;        // q_c -> v_c -> k_s
        __bf16* Bf = A + PROJ;             // k_c -> q_s
        __bf16* D  = Bf + PROJ;            // v_s: 8192x128 row-major
        float*  Sb = (float*)(D + 1048576);
        __bf16* Pb = (__bf16*)(Sb + 65536);
        int*  flag = (int*)(Pb + 65536);

        detect_dtype<<<dim3(1), dim3(64), 0, stream>>>((const unsigned*)t1, flag);

        auto mk2 = [&](const void* X0, const void* W0, __bf16* Y0, int K0, int t0,
                       const void* X1, const void* W1, __bf16* Y1, int K1, int t1_) {
            ProjArgs p{};
            p.ng = 2;
            p.X[0] = X0; p.W[0] = W0; p.Y[0] = Y0; p.K[0] = K0;
            p.X[1] = X1; p.W[1] = W1; p.Y[1] = Y1; p.K[1] = K1;
            p.yofs[0] = 0; p.yofs[1] = t0; p.yofs[2] = t0 + t1_;
            return p;
        };

        const size_t fb_end = (size_t)((char*)(flag + 1) - (char*)d_ws);
        const size_t pofs = (fb_end + 255) & ~(size_t)255;
        const size_t per_split = (1048576 + 65536) * 4;  // flash po + pl bytes/split
        int nspl = 1;
        if (ws_size >= pofs + 4 * per_split)      nspl = 4;
        else if (ws_size >= pofs + 2 * per_split) nspl = 2;
        const bool qk_part = (ws_size >= pofs + QK_BYTES);
        float* scratch = (float*)((char*)d_ws + pofs);

        ProjArgs p1 = mk2(s,  Wq_c, A,  512, 4, sh, Wk_c, Bf, 512, 4);
        proj_gemm<<<dim3(64, 8), blk, 0, stream>>>(p1, flag);
        if (qk_part) {
            chan_qk<0><<<dim3(512), blk, 0, stream>>>(A, Bf, scratch);
            chan_softmax<32><<<dim3(256), blk, 0, stream>>>(scratch, t1, Pb, flag);
        } else {
            zero_f32<<<dim3(256), blk, 0, stream>>>(Sb, 65536);
            chan_qk<1><<<dim3(512), blk, 0, stream>>>(A, Bf, Sb);
            chan_softmax<1><<<dim3(256), blk, 0, stream>>>(Sb, t1, Pb, flag);
        }

        ProjArgs p2 = mk2(sh, Wv_c, A, 512, 4, sh, Wq_s, Bf, 512, 4);
        proj_gemm<<<dim3(64, 8), blk, 0, stream>>>(p2, flag);
        chan_av<<<dim3(1024), blk, 0, stream>>>(Pb, A, d_out, flag);

        ProjArgs p3 = mk2(sh, Wk_s, A, 512, 4, h_, Wv_s, D, 128, 1);
        proj_gemm<<<dim3(64, 5), blk, 0, stream>>>(p3, flag);

        float* po = scratch;
        float* pl = po + (size_t)nspl * 1048576;
        flash_sa<1><<<dim3(256, nspl), dim3(512), 0, stream>>>(Bf, A, D, t2, d_out, po, pl, flag);
        if (nspl > 1)
            flash_combine<<<dim3(256), blk, 0, stream>>>(po, pl, d_out, flag, nspl);
    }
}